// Round 4
// baseline (154.095 us; speedup 1.0000x reference)
//
#include <hip/hip_runtime.h>

#define HH 256
#define WW 256
#define CC 3
#define KK 9
#define OC 64
#define KD 27     // C*K flattened reduction dim
#define PSTS 40   // patch/S row stride in shorts (80 B, 16B-aligned)
#define DROWB 96  // D row stride in bytes (18 f32 + 9 bf16 + pad)
#define WRB 6144  // per-wave LDS region = 64 rows * 96 B

typedef __attribute__((ext_vector_type(8))) short bf16x8;
typedef __attribute__((ext_vector_type(4))) float f32x4;
typedef __attribute__((ext_vector_type(2))) float f32x2;

// round-to-nearest-even f32 -> bf16
static __device__ __forceinline__ short f2bf(float f) {
    unsigned u = __float_as_uint(f);
    return (short)((u + 0x7fffu + ((u >> 16) & 1u)) >> 16);
}
static __device__ __forceinline__ unsigned pack2(short a, short b) {
    return (unsigned)(unsigned short)a | ((unsigned)(unsigned short)b << 16);
}
static __device__ __forceinline__ float bf2f(unsigned h) {
    return __uint_as_float(h << 16);
}

__global__ __launch_bounds__(256, 6) void dcn_fused(
    const float* __restrict__ x,        // (B,3,256,256)
    const float* __restrict__ w_offset, // (18,27)
    const float* __restrict__ b_offset, // (18)
    const float* __restrict__ w_mask,   // (9,27)
    const float* __restrict__ b_mask,   // (9)
    const float* __restrict__ w_conv,   // (64,27)
    float* __restrict__ out)            // (B,64,256,256)
{
    __shared__ __align__(16) char LDSBUF[4 * WRB];  // 24576 B -> 6 blocks/CU

    const int tid = threadIdx.x;        // pixel column j
    const int j = tid;
    const int i = blockIdx.x & (HH - 1);
    const int b = blockIdx.x >> 8;
    const int lane = tid & 63;
    const int wv = tid >> 6;
    const int fm = lane & 15;           // fragment row/col index
    const int kc = lane >> 4;           // k-chunk 0..3

    char* wbase = LDSBUF + wv * WRB;
    short* patchS = (short*)wbase;      // patch rows, later S rows (80 B stride)

    const float* xb = x + (size_t)b * CC * HH * WW;

    // ================= phase 1: patch load + bf16(hi) staging =================
    float xv[32];
#pragma unroll
    for (int c = 0; c < CC; ++c) {
#pragma unroll
        for (int p = 0; p < 3; ++p) {
            int y = i + p - 1;
            bool yok = (unsigned)y < HH;
#pragma unroll
            for (int q = 0; q < 3; ++q) {
                int xx = j + q - 1;
                bool ok = yok && ((unsigned)xx < WW);
                xv[c * 9 + p * 3 + q] = ok ? xb[((size_t)c * HH + y) * WW + xx] : 0.0f;
            }
        }
    }
#pragma unroll
    for (int kd = KD; kd < 32; ++kd) xv[kd] = 0.0f;

    {
        short* rp = patchS + lane * PSTS;
#pragma unroll
        for (int o = 0; o < 4; ++o) {
            bf16x8 vh;
#pragma unroll
            for (int e = 0; e < 8; ++e) vh[e] = f2bf(xv[o * 8 + e]);
            *(bf16x8*)(rp + o * 8) = vh;
        }
    }

    // ================= conv weight fragments (hi/lo) + bias ====================
    bf16x8 whi[2], wlo[2];
#pragma unroll
    for (int t = 0; t < 2; ++t) {
        int ch = t * 16 + fm;           // 0..17 offset, 18..26 mask, 27..31 zero
        int cho = min(ch, 17);
        int chm = min(max(ch - 18, 0), 8);
#pragma unroll
        for (int e = 0; e < 8; ++e) {
            int kd = kc * 8 + e;
            int kdc = (kd < KD) ? kd : 0;
            float wo = w_offset[cho * KD + kdc];
            float wm = w_mask[chm * KD + kdc];
            float val = (kd < KD) ? (ch < 18 ? wo : (ch < KD ? wm : 0.0f)) : 0.0f;
            unsigned u = __float_as_uint(val);
            whi[t][e] = (short)(u >> 16);
            float d = val - __uint_as_float(u & 0xffff0000u);
            wlo[t][e] = (short)(__float_as_uint(d) >> 16);
        }
    }
    f32x4 cbias[2];
#pragma unroll
    for (int t = 0; t < 2; ++t) {
#pragma unroll
        for (int r = 0; r < 4; ++r) {
            int ch = t * 16 + kc * 4 + r;
            float bo = b_offset[min(ch, 17)];
            float bm = b_mask[min(max(ch - 18, 0), 8)];
            cbias[t][r] = ch < 18 ? bo : (ch < KD ? bm : 0.0f);
        }
    }

    // ============ conv MFMA: D[32ch][64px] = (Whi+Wlo)*Phi + bias =============
    // read ALL patch rows before any D write (regions alias across lanes)
    f32x4 dacc[4][2];
#pragma unroll
    for (int g = 0; g < 4; ++g) {
        bf16x8 phi = *(const bf16x8*)(patchS + (g * 16 + fm) * PSTS + kc * 8);
#pragma unroll
        for (int t = 0; t < 2; ++t) {
            f32x4 a = __builtin_amdgcn_mfma_f32_16x16x32_bf16(whi[t], phi, cbias[t], 0, 0, 0);
            a = __builtin_amdgcn_mfma_f32_16x16x32_bf16(wlo[t], phi, a, 0, 0, 0);
            dacc[g][t] = a;
        }
    }
    // D row layout (96 B): [0..71] dy/dx f32 pairs k=0..8, [72..89] mask z bf16
#pragma unroll
    for (int g = 0; g < 4; ++g) {
        char* dr = wbase + (g * 16 + fm) * DROWB;
        *(f32x4*)(dr + kc * 16) = dacc[g][0];           // ch kc*4..kc*4+3 (dy/dx 0..7)
        f32x4 a1 = dacc[g][1];                          // ch 16+kc*4..16+kc*4+3
        if (kc == 0) {
            *(f32x2*)(dr + 64) = (f32x2){a1[0], a1[1]};             // dy8,dx8
            *(unsigned*)(dr + 72) = pack2(f2bf(a1[2]), f2bf(a1[3])); // z0,z1
        } else if (kc == 1) {
            *(unsigned*)(dr + 76) = pack2(f2bf(a1[0]), f2bf(a1[1])); // z2,z3
            *(unsigned*)(dr + 80) = pack2(f2bf(a1[2]), f2bf(a1[3])); // z4,z5
        } else if (kc == 2) {
            *(unsigned*)(dr + 84) = pack2(f2bf(a1[0]), f2bf(a1[1])); // z6,z7
            *(short*)(dr + 88) = f2bf(a1[2]);                        // z8
        }
    }

    // ============ read ENTIRE D row into registers (before S writes!) =========
    const char* myD = wbase + lane * DROWB;
    f32x4 d03 = *(const f32x4*)(myD);        // dy0 dx0 dy1 dx1
    f32x4 d47 = *(const f32x4*)(myD + 16);   // dy2 dx2 dy3 dx3
    f32x4 d8b = *(const f32x4*)(myD + 32);   // dy4 dx4 dy5 dx5
    f32x4 dcf = *(const f32x4*)(myD + 48);   // dy6 dx6 dy7 dx7
    f32x2 d8p = *(const f32x2*)(myD + 64);   // dy8 dx8
    unsigned mz01 = *(const unsigned*)(myD + 72);
    unsigned mz23 = *(const unsigned*)(myD + 76);
    unsigned mz45 = *(const unsigned*)(myD + 80);
    unsigned mz67 = *(const unsigned*)(myD + 84);
    unsigned mz8  = *(const unsigned short*)(myD + 88);

    const float dyv[9] = {d03[0], d03[2], d47[0], d47[2], d8b[0], d8b[2], dcf[0], dcf[2], d8p[0]};
    const float dxv[9] = {d03[1], d03[3], d47[1], d47[3], d8b[1], d8b[3], dcf[1], dcf[3], d8p[1]};
    const unsigned mzv[9] = {mz01 & 0xffffu, mz01 >> 16, mz23 & 0xffffu, mz23 >> 16,
                             mz45 & 0xffffu, mz45 >> 16, mz67 & 0xffffu, mz67 >> 16, mz8};

    // S row: zero-pad shorts 27..31 (bytes 54..63) — safe: all D reads issued above
    short* srow = patchS + lane * PSTS;
    srow[27] = 0;
    *(f32x2*)((char*)srow + 56) = (f32x2){0.0f, 0.0f};

    // ================= sampling: gathers + per-k S staging ====================
#pragma unroll
    for (int k = 0; k < KK; ++k) {
        float dy = dyv[k], dx = dxv[k];
        float mzf = bf2f(mzv[k]);
        float msk = 1.0f / (1.0f + __expf(-mzf));

        float py = (float)(i + (k / 3) - 1) + dy;
        float px = (float)(j + (k % 3) - 1) + dx;
        float y0f = floorf(py), x0f = floorf(px);
        float wy = py - y0f, wx = px - x0f;
        int y0 = (int)y0f, x0 = (int)x0f;
        int y1 = y0 + 1, x1 = x0 + 1;

        float w00 = (1.0f - wy) * (1.0f - wx);
        float w01 = (1.0f - wy) * wx;
        float w10 = wy * (1.0f - wx);
        float w11 = wy * wx;

        bool v0y = (unsigned)y0 < HH, v1y = (unsigned)y1 < HH;
        bool v0x = (unsigned)x0 < WW, v1x = (unsigned)x1 < WW;
        int y0c = min(max(y0, 0), HH - 1), y1c = min(max(y1, 0), HH - 1);
        int x0c = min(max(x0, 0), WW - 1), x1c = min(max(x1, 0), WW - 1);

        float f00 = (v0y && v0x) ? w00 : 0.0f;
        float f01 = (v0y && v1x) ? w01 : 0.0f;
        float f10 = (v1y && v0x) ? w10 : 0.0f;
        float f11 = (v1y && v1x) ? w11 : 0.0f;

        int o00 = y0c * WW + x0c, o01 = y0c * WW + x1c;
        int o10 = y1c * WW + x0c, o11 = y1c * WW + x1c;

#pragma unroll
        for (int c = 0; c < CC; ++c) {
            const float* xc = xb + (size_t)c * HH * WW;
            float v00 = xc[o00];
            float v01 = xc[o01];
            float v10 = xc[o10];
            float v11 = xc[o11];
            float s = (v00 * f00 + v01 * f01 + v10 * f10 + v11 * f11) * msk;
            srow[c * KK + k] = f2bf(s);   // ds_write_b16, static offset
        }
    }

    // ================= MFMA epilogue: out[64oc x 64px per wave] ===============
    bf16x8 afrag[4];
#pragma unroll
    for (int t = 0; t < 4; ++t) {
#pragma unroll
        for (int e = 0; e < 8; ++e) {
            int kd = kc * 8 + e;
            afrag[t][e] = (kd < KD) ? f2bf(w_conv[(t * 16 + fm) * KD + kd]) : (short)0;
        }
    }

#pragma unroll
    for (int g = 0; g < 4; ++g) {
        int jj = wv * 64 + g * 16 + fm;
        bf16x8 bfrag = *(const bf16x8*)(patchS + (g * 16 + fm) * PSTS + kc * 8);

        f32x4 acc[4];
#pragma unroll
        for (int t = 0; t < 4; ++t) {
            acc[t] = (f32x4){0.f, 0.f, 0.f, 0.f};
            acc[t] = __builtin_amdgcn_mfma_f32_16x16x32_bf16(afrag[t], bfrag, acc[t], 0, 0, 0);
        }

        float* op = out + (((size_t)b * OC) * HH + i) * WW + jj;
#pragma unroll
        for (int t = 0; t < 4; ++t) {
#pragma unroll
            for (int r = 0; r < 4; ++r) {
                op[(size_t)(t * 16 + kc * 4 + r) * (HH * WW)] = acc[t][r];
            }
        }
    }
}

extern "C" void kernel_launch(void* const* d_in, const int* in_sizes, int n_in,
                              void* d_out, int out_size, void* d_ws, size_t ws_size,
                              hipStream_t stream) {
    const float* x        = (const float*)d_in[0];
    const float* w_offset = (const float*)d_in[1];
    const float* b_offset = (const float*)d_in[2];
    const float* w_mask   = (const float*)d_in[3];
    const float* b_mask   = (const float*)d_in[4];
    const float* w_conv   = (const float*)d_in[5];
    float* out = (float*)d_out;

    int B = in_sizes[0] / (CC * HH * WW);  // 16
    dim3 grid(B * HH);                     // one block per (b, row)
    dim3 block(WW);                        // one thread per column
    hipLaunchKernelGGL(dcn_fused, grid, block, 0, stream,
                       x, w_offset, b_offset, w_mask, b_mask, w_conv, out);
}

// Round 5
// 150.389 us; speedup vs baseline: 1.0246x; 1.0246x over previous
//
#include <hip/hip_runtime.h>

#define HH 256
#define WW 256
#define CC 3
#define KK 9
#define OC 64
#define KD 27
#define PSTS 40     // 80 B row stride: patch -> D -> S overlay region (proven 0-conflict b128 pattern)
#define MOFF 5120   // mask-z region offset within per-wave LDS region
#define MST 24      // mask row stride bytes
#define WRB 6656    // per-wave LDS bytes (5120 + 1536)

typedef __attribute__((ext_vector_type(8))) short bf16x8;
typedef __attribute__((ext_vector_type(4))) float f32x4;
typedef __attribute__((ext_vector_type(2))) float f32x2;
typedef __attribute__((ext_vector_type(4))) unsigned int u32x4;

static __device__ __forceinline__ short f2bf(float f) {
    unsigned u = __float_as_uint(f);
    return (short)((u + 0x7fffu + ((u >> 16) & 1u)) >> 16);
}
static __device__ __forceinline__ unsigned pack2(short a, short b) {
    return (unsigned)(unsigned short)a | ((unsigned)(unsigned short)b << 16);
}
static __device__ __forceinline__ float bfhi(unsigned u) { return __uint_as_float(u << 16); }          // low short
static __device__ __forceinline__ float bflo(unsigned u) { return __uint_as_float(u & 0xffff0000u); }  // high short

// ============================ prep kernel =================================
// xtA: NHWC bf16 pad4 (npix entries of 8B, pixel pairs (2t,2t+1) 16B-aligned)
// xtB (at xtA + npix*4 shorts): shifted pairs (2t+1, 2t+2)
// wcf: w_conv MFMA A-fragments, 64 lanes x 32 shorts
// wof: offset/mask conv W hi/lo frags + bias, 64 lanes x 96 B
__global__ __launch_bounds__(256) void dcn_prep(
    const float* __restrict__ x,
    const float* __restrict__ w_offset, const float* __restrict__ b_offset,
    const float* __restrict__ w_mask,   const float* __restrict__ b_mask,
    const float* __restrict__ w_conv,
    short* __restrict__ xtA, short* __restrict__ wcf, char* __restrict__ wof,
    int npix)
{
    const int tid = threadIdx.x;
    if (blockIdx.x == gridDim.x - 1) {
        if (tid < 64) {
            const int fm = tid & 15, kc = tid >> 4;
#pragma unroll
            for (int t = 0; t < 4; ++t) {
                bf16x8 v;
#pragma unroll
                for (int e = 0; e < 8; ++e) {
                    int kd = kc * 8 + e;
                    v[e] = (kd < KD) ? f2bf(w_conv[(t * 16 + fm) * KD + kd]) : (short)0;
                }
                *(bf16x8*)(wcf + tid * 32 + t * 8) = v;
            }
#pragma unroll
            for (int t = 0; t < 2; ++t) {
                int ch = t * 16 + fm;
                bf16x8 vh, vl;
#pragma unroll
                for (int e = 0; e < 8; ++e) {
                    int kd = kc * 8 + e;
                    float val = 0.0f;
                    if (kd < KD) {
                        if (ch < 18) val = w_offset[ch * KD + kd];
                        else if (ch < KD) val = w_mask[(ch - 18) * KD + kd];
                    }
                    unsigned u = __float_as_uint(val);
                    vh[e] = (short)(u >> 16);
                    float d = val - __uint_as_float(u & 0xffff0000u);
                    vl[e] = (short)(__float_as_uint(d) >> 16);
                }
                *(bf16x8*)(wof + tid * 96 + t * 16) = vh;
                *(bf16x8*)(wof + tid * 96 + 32 + t * 16) = vl;
            }
#pragma unroll
            for (int t = 0; t < 2; ++t) {
                f32x4 cb;
#pragma unroll
                for (int r = 0; r < 4; ++r) {
                    int ch = t * 16 + kc * 4 + r;
                    float v = 0.0f;
                    if (ch < 18) v = b_offset[ch];
                    else if (ch < KD) v = b_mask[ch - 18];
                    cb[r] = v;
                }
                *(f32x4*)(wof + tid * 96 + 64 + t * 16) = cb;
            }
        }
        return;
    }

    const int p0 = (blockIdx.x * 256 + tid) * 4;   // 4 consecutive pixels
    if (p0 >= npix) return;
    const int bb = p0 >> 16;
    const int q  = p0 & 0xffff;
    const float* xb = x + (size_t)bb * (3 * 65536) + q;
    f32x4 r0 = *(const f32x4*)(xb);
    f32x4 r1 = *(const f32x4*)(xb + 65536);
    f32x4 r2 = *(const f32x4*)(xb + 131072);
    float e0 = 0.f, e1 = 0.f, e2 = 0.f;          // 5th pixel for shifted pairs
    int p4 = p0 + 4;
    if (p4 < npix) {
        int b4 = p4 >> 16, q4 = p4 & 0xffff;
        const float* x4 = x + (size_t)b4 * (3 * 65536) + q4;
        e0 = x4[0]; e1 = x4[65536]; e2 = x4[131072];
    }
    short s0 = f2bf(r0[0]), s1 = f2bf(r1[0]), s2 = f2bf(r2[0]);
    short t0 = f2bf(r0[1]), t1 = f2bf(r1[1]), t2 = f2bf(r2[1]);
    short u0 = f2bf(r0[2]), u1 = f2bf(r1[2]), u2 = f2bf(r2[2]);
    short v0 = f2bf(r0[3]), v1 = f2bf(r1[3]), v2 = f2bf(r2[3]);
    short w0 = f2bf(e0),   w1 = f2bf(e1),   w2 = f2bf(e2);

    short* A = xtA + (size_t)p0 * 4;
    *(bf16x8*)A       = (bf16x8){s0, s1, s2, 0, t0, t1, t2, 0};
    *(bf16x8*)(A + 8) = (bf16x8){u0, u1, u2, 0, v0, v1, v2, 0};

    short* Bb = xtA + (size_t)npix * 4;
    size_t ent = ((size_t)(p0 >> 8) << 7) + (size_t)((p0 & 255) >> 1);
    *(bf16x8*)(Bb + ent * 8)       = (bf16x8){t0, t1, t2, 0, u0, u1, u2, 0};
    *(bf16x8*)(Bb + (ent + 1) * 8) = (bf16x8){v0, v1, v2, 0, w0, w1, w2, 0};
}

// ============================ main kernel =================================
__global__ __launch_bounds__(256, 4) void dcn_main(
    const float* __restrict__ x,
    const short* __restrict__ xt,    // A, with B at + npix*4 shorts
    const short* __restrict__ wcf,
    const char*  __restrict__ wof,
    float* __restrict__ out,
    int npix)
{
    __shared__ __align__(16) char LDSBUF[4 * WRB];   // 26624 B

    const int tid = threadIdx.x;
    const int j = tid;
    const int i = blockIdx.x & (HH - 1);
    const int b = blockIdx.x >> 8;
    const int lane = tid & 63;
    const int wv = tid >> 6;
    const int fm = lane & 15;
    const int kc = lane >> 4;

    char* wbase = LDSBUF + wv * WRB;
    short* patchS = (short*)wbase;

    const float* xb = x + (size_t)b * CC * HH * WW;

    // ---- patch: 27 coalesced f32 loads -> bf16(hi) LDS row ----
    float xv[32];
#pragma unroll
    for (int c = 0; c < CC; ++c) {
#pragma unroll
        for (int p = 0; p < 3; ++p) {
            int y = i + p - 1;
            bool yok = (unsigned)y < HH;
#pragma unroll
            for (int qq = 0; qq < 3; ++qq) {
                int xx = j + qq - 1;
                bool ok = yok && ((unsigned)xx < WW);
                xv[c * 9 + p * 3 + qq] = ok ? xb[((size_t)c * HH + y) * WW + xx] : 0.0f;
            }
        }
    }
    {
        short* rp = patchS + lane * PSTS;
#pragma unroll
        for (int o = 0; o < 4; ++o) {
            bf16x8 vh;
#pragma unroll
            for (int e = 0; e < 8; ++e) {
                int kd = o * 8 + e;
                vh[e] = (kd < KD) ? f2bf(xv[kd]) : (short)0;
            }
            *(bf16x8*)(rp + o * 8) = vh;
        }
    }

    // ---- conv W fragments from prepacked ws ----
    const char* wl = wof + lane * 96;
    bf16x8 whi0 = *(const bf16x8*)(wl);
    bf16x8 whi1 = *(const bf16x8*)(wl + 16);
    bf16x8 wlo0 = *(const bf16x8*)(wl + 32);
    bf16x8 wlo1 = *(const bf16x8*)(wl + 48);
    f32x4 cb0 = *(const f32x4*)(wl + 64);
    f32x4 cb1 = *(const f32x4*)(wl + 80);

    // ---- conv MFMA: D[32ch][64px] (reads all patch rows before D writes) ----
    f32x4 dacc[4][2];
#pragma unroll
    for (int g = 0; g < 4; ++g) {
        bf16x8 phi = *(const bf16x8*)(patchS + (g * 16 + fm) * PSTS + kc * 8);
        f32x4 a0 = __builtin_amdgcn_mfma_f32_16x16x32_bf16(whi0, phi, cb0, 0, 0, 0);
        a0 = __builtin_amdgcn_mfma_f32_16x16x32_bf16(wlo0, phi, a0, 0, 0, 0);
        f32x4 a1 = __builtin_amdgcn_mfma_f32_16x16x32_bf16(whi1, phi, cb1, 0, 0, 0);
        a1 = __builtin_amdgcn_mfma_f32_16x16x32_bf16(wlo1, phi, a1, 0, 0, 0);
        dacc[g][0] = a0;
        dacc[g][1] = a1;
    }
    // D rows (stride 80B): 16 f32 dy/dx (ch0..15) + dy8,dx8 @64; mask z bf16 in M region
#pragma unroll
    for (int g = 0; g < 4; ++g) {
        int r = g * 16 + fm;
        char* dr = wbase + r * 80;
        char* mr = wbase + MOFF + r * MST;
        *(f32x4*)(dr + kc * 16) = dacc[g][0];
        f32x4 a1 = dacc[g][1];
        if (kc == 0) {
            *(f32x2*)(dr + 64) = (f32x2){a1[0], a1[1]};                       // dy8, dx8
            *(unsigned*)(mr + 0) = pack2(f2bf(a1[2]), f2bf(a1[3]));           // z0, z1
        } else if (kc == 1) {
            *(unsigned*)(mr + 4) = pack2(f2bf(a1[0]), f2bf(a1[1]));           // z2, z3
            *(unsigned*)(mr + 8) = pack2(f2bf(a1[2]), f2bf(a1[3]));           // z4, z5
        } else if (kc == 2) {
            *(unsigned*)(mr + 12) = pack2(f2bf(a1[0]), f2bf(a1[1]));          // z6, z7
            *(unsigned short*)(mr + 16) = (unsigned short)f2bf(a1[2]);        // z8
        }
    }

    // ---- read own D row fully (b128 pattern) before S overwrites it ----
    const char* myD = wbase + lane * 80;
    f32x4 d03 = *(const f32x4*)(myD);
    f32x4 d47 = *(const f32x4*)(myD + 16);
    f32x4 d8b = *(const f32x4*)(myD + 32);
    f32x4 dcf = *(const f32x4*)(myD + 48);
    f32x2 d8p = *(const f32x2*)(myD + 64);
    const float dyv[9] = {d03[0], d03[2], d47[0], d47[2], d8b[0], d8b[2], dcf[0], dcf[2], d8p[0]};
    const float dxv[9] = {d03[1], d03[3], d47[1], d47[3], d8b[1], d8b[3], dcf[1], dcf[3], d8p[1]};
    const unsigned short* mrow = (const unsigned short*)(wbase + MOFF + lane * MST);

    // ---- epilogue A-fragments from prepacked ws (issue early) ----
    bf16x8 afrag[4];
#pragma unroll
    for (int t = 0; t < 4; ++t) afrag[t] = *(const bf16x8*)(wcf + lane * 32 + t * 8);

    // ---- sampling: 2 aligned 16B gathers per k from NHWC-bf16 (A/B parity) ----
    const size_t boff = (size_t)npix * 4;   // shorts offset of shifted buffer
    float s27[KD];
#pragma unroll
    for (int k = 0; k < KK; ++k) {
        float dy = dyv[k], dx = dxv[k];
        float msk = 1.0f / (1.0f + __expf(-bfhi((unsigned)mrow[k])));

        float py = (float)(i + (k / 3) - 1) + dy;
        float px = (float)(j + (k % 3) - 1) + dx;
        float y0f = floorf(py), x0f = floorf(px);
        float wy = py - y0f, wx = px - x0f;
        int y0 = (int)y0f, x0 = (int)x0f;
        int y1 = y0 + 1, x1 = x0 + 1;

        float w00 = (1.0f - wy) * (1.0f - wx);
        float w01 = (1.0f - wy) * wx;
        float w10 = wy * (1.0f - wx);
        float w11 = wy * wx;

        bool v0y = (unsigned)y0 < HH, v1y = (unsigned)y1 < HH;
        bool v0x = (unsigned)x0 < WW, v1x = (unsigned)x1 < WW;
        float f00 = (v0y && v0x) ? w00 : 0.0f;
        float f01 = (v0y && v1x) ? w01 : 0.0f;
        float f10 = (v1y && v0x) ? w10 : 0.0f;
        float f11 = (v1y && v1x) ? w11 : 0.0f;

        int ly0 = min(max(y0, 0), HH - 1);
        int ly1 = min(max(y1, 0), HH - 1);
        int lx  = min(max(x0, 0), WW - 2);
        bool sw = (x0 != lx);                 // loaded pair is (lx, lx+1)
        const short* base = xt + (size_t)(lx & 1) * boff;
        int tt = lx >> 1;

        u32x4 r0v = *(const u32x4*)(base + ((size_t)((b * HH + ly0) * 128 + tt)) * 8);
        u32x4 r1v = *(const u32x4*)(base + ((size_t)((b * HH + ly1) * 128 + tt)) * 8);

        float a0 = sw ? f01 : f00, b0 = sw ? f00 : f01;   // weights for (lo, hi) pixels
        float a1 = sw ? f11 : f10, b1 = sw ? f10 : f11;

        float s0 = fmaf(bfhi(r0v[0]), a0, fmaf(bfhi(r0v[2]), b0, fmaf(bfhi(r1v[0]), a1, bfhi(r1v[2]) * b1)));
        float s1 = fmaf(bflo(r0v[0]), a0, fmaf(bflo(r0v[2]), b0, fmaf(bflo(r1v[0]), a1, bflo(r1v[2]) * b1)));
        float s2 = fmaf(bfhi(r0v[1]), a0, fmaf(bfhi(r0v[3]), b0, fmaf(bfhi(r1v[1]), a1, bfhi(r1v[3]) * b1)));
        s27[0 + k]  = s0 * msk;
        s27[9 + k]  = s1 * msk;
        s27[18 + k] = s2 * msk;
    }

    // ---- S rows: proven stride-80 b128 writes ----
    {
        short* srow = patchS + lane * PSTS;
#pragma unroll
        for (int o = 0; o < 4; ++o) {
            bf16x8 v;
#pragma unroll
            for (int e = 0; e < 8; ++e) {
                int kd = o * 8 + e;
                v[e] = (kd < KD) ? f2bf(s27[kd]) : (short)0;
            }
            *(bf16x8*)(srow + o * 8) = v;
        }
    }

    // ---- MFMA epilogue: out[64oc x 64px per wave] ----
#pragma unroll
    for (int g = 0; g < 4; ++g) {
        int jj = wv * 64 + g * 16 + fm;
        bf16x8 bfrag = *(const bf16x8*)(patchS + (g * 16 + fm) * PSTS + kc * 8);

        f32x4 acc[4];
#pragma unroll
        for (int t = 0; t < 4; ++t) {
            acc[t] = (f32x4){0.f, 0.f, 0.f, 0.f};
            acc[t] = __builtin_amdgcn_mfma_f32_16x16x32_bf16(afrag[t], bfrag, acc[t], 0, 0, 0);
        }

        float* op = out + (((size_t)b * OC) * HH + i) * WW + jj;
#pragma unroll
        for (int t = 0; t < 4; ++t) {
#pragma unroll
            for (int r = 0; r < 4; ++r) {
                op[(size_t)(t * 16 + kc * 4 + r) * (HH * WW)] = acc[t][r];
            }
        }
    }
}

extern "C" void kernel_launch(void* const* d_in, const int* in_sizes, int n_in,
                              void* d_out, int out_size, void* d_ws, size_t ws_size,
                              hipStream_t stream) {
    const float* x        = (const float*)d_in[0];
    const float* w_offset = (const float*)d_in[1];
    const float* b_offset = (const float*)d_in[2];
    const float* w_mask   = (const float*)d_in[3];
    const float* b_mask   = (const float*)d_in[4];
    const float* w_conv   = (const float*)d_in[5];
    float* out = (float*)d_out;

    int B = in_sizes[0] / (CC * HH * WW);   // 16
    int npix = B * HH * WW;                 // 1,048,576

    // ws layout: xtA (npix*8 B) | xtB (npix*8 B) | wcf 4096 B | wof 6144 B
    short* xtA = (short*)d_ws;
    short* wcf = (short*)((char*)d_ws + (size_t)npix * 16);
    char*  wof = (char*)d_ws + (size_t)npix * 16 + 4096;

    int nb = (npix + 1023) / 1024;          // 4 px per thread
    hipLaunchKernelGGL(dcn_prep, dim3(nb + 1), dim3(256), 0, stream,
                       x, w_offset, b_offset, w_mask, b_mask, w_conv,
                       xtA, wcf, wof, npix);

    hipLaunchKernelGGL(dcn_main, dim3(B * HH), dim3(256), 0, stream,
                       x, xtA, wcf, wof, out, npix);
}